// Round 1
// 1899.630 us; speedup vs baseline: 1.2204x; 1.2204x over previous
//
#include <hip/hip_runtime.h>
#include <stdint.h>
#include <stddef.h>

#define HID    1024
#define NHEADS 16
#define HD     64
#define BATCH  4
#define SEQ    2048

typedef __attribute__((ext_vector_type(8))) short short8;
typedef __attribute__((ext_vector_type(4))) short short4v;
typedef __attribute__((ext_vector_type(4))) float float4v;

static __device__ __forceinline__ short f2bf(float f) {
    unsigned u = __builtin_bit_cast(unsigned, f);
    u += 0x7fffu + ((u >> 16) & 1u);   // RNE
    return (short)(u >> 16);
}

#define GLD_LDS16(g, l)                                        \
    __builtin_amdgcn_global_load_lds(                          \
        (__attribute__((address_space(1))) void*)(g),          \
        (__attribute__((address_space(3))) void*)(l), 16, 0, 0)

// ---------------- fp32 -> bf16 elementwise convert ----------------
__global__ __launch_bounds__(256) void cvt_f32_bf16(const float* __restrict__ in,
                                                    short* __restrict__ out, int n4) {
    int i = blockIdx.x * 256 + threadIdx.x;
    if (i < n4) {
        float4v v = ((const float4v*)in)[i];
        short4v o;
        o[0] = f2bf(v[0]); o[1] = f2bf(v[1]); o[2] = f2bf(v[2]); o[3] = f2bf(v[3]);
        ((short4v*)out)[i] = o;
    }
}

// ---------------- GEMM: C[M,N] = A[M,K] * W[N,K]^T + bias  (m97 structure) ----
// A bf16 [8192,1024], W bf16 [1024,1024]. Tile 128x128, BK=32, 256 thr = 4 waves,
// wave computes 64x64 (4x4 fragments of 16x16x32 MFMA).
// MODE 1: bf16 out in Vt layout (B,H,HD,S)
// MODE 2: fp32 row-major out (final O projection)
// MODE 3: bf16 out head-major (B,H,S,HD)   (Q,K projections)
// Grid: 512 linear blocks, XCD-chunked swizzle (64 M-tiles x 8 N-tiles).
template<int MODE>
__global__ __launch_bounds__(256) void gemm_bf16(const short* __restrict__ A,
                                                 const short* __restrict__ Wb,
                                                 const float* __restrict__ bias,
                                                 void* __restrict__ outp) {
    __shared__ short As[128 * 32];
    __shared__ short Bs[128 * 32];

    const int id = blockIdx.x;
    // XCD k (id%8) gets M-tiles [8k, 8k+8) x all 8 N-tiles -> A panel L2-local.
    const int xt = (id & 7) * 8 + ((id >> 3) & 7);   // 0..63  M-tile
    const int yt = id >> 6;                           // 0..7   N-tile
    const int m0 = xt * 128;
    const int n0 = yt * 128;

    const int t    = threadIdx.x;
    const int lane = t & 63;
    const int w    = t >> 6;
    const int l15  = lane & 15;
    const int quad = lane >> 4;
    const int wm   = (w >> 1) * 64;
    const int wn   = (w & 1) * 64;

    float4v acc[4][4];
#pragma unroll
    for (int i = 0; i < 4; i++)
#pragma unroll
        for (int j = 0; j < 4; j++)
#pragma unroll
            for (int r = 0; r < 4; r++) acc[i][j][r] = 0.0f;

    const int tr = t >> 2;          // 0..63 : row within half-tile
    const int tc = (t & 3) * 8;     // 0,8,16,24 : k-offset (shorts)
    const short* Ag = A  + (size_t)(m0 + tr) * 1024 + tc;
    const short* Wg = Wb + (size_t)(n0 + tr) * 1024 + tc;
    short* a_dst = As + t * 8;      // wave-linear: base + lane*16B
    short* b_dst = Bs + t * 8;

    for (int ks = 0; ks < 1024; ks += 32) {
        __syncthreads();            // protect LDS from previous iter's reads
        GLD_LDS16(Ag + ks,             a_dst);
        GLD_LDS16(Ag + 64 * 1024 + ks, a_dst + 2048);
        GLD_LDS16(Wg + ks,             b_dst);
        GLD_LDS16(Wg + 64 * 1024 + ks, b_dst + 2048);
        __syncthreads();            // compiler emits vmcnt(0) drain here

        short8 af[4], bfr[4];
#pragma unroll
        for (int mi = 0; mi < 4; mi++)
            af[mi] = *(const short8*)(As + (wm + mi * 16 + l15) * 32 + quad * 8);
#pragma unroll
        for (int ni = 0; ni < 4; ni++)
            bfr[ni] = *(const short8*)(Bs + (wn + ni * 16 + l15) * 32 + quad * 8);
#pragma unroll
        for (int mi = 0; mi < 4; mi++)
#pragma unroll
            for (int ni = 0; ni < 4; ni++)
                acc[mi][ni] = __builtin_amdgcn_mfma_f32_16x16x32_bf16(
                    af[mi], bfr[ni], acc[mi][ni], 0, 0, 0);
    }

    // epilogue: lane holds col n (l15), rows m = quad*4 + r
#pragma unroll
    for (int ni = 0; ni < 4; ni++) {
        const int n = n0 + wn + ni * 16 + l15;
        const float bv = bias[n];
#pragma unroll
        for (int mi = 0; mi < 4; mi++) {
            const int mb = m0 + wm + mi * 16 + quad * 4;
            if (MODE == 3) {                 // bf16 (B,H,S,HD)
                short* ob = (short*)outp;
                const int h_ = n >> 6, d_ = n & 63;
                const int b_ = mb >> 11;
#pragma unroll
                for (int r = 0; r < 4; r++) {
                    const int s_ = (mb + r) & 2047;
                    ob[((size_t)(b_ * NHEADS + h_) * SEQ + s_) * HD + d_] =
                        f2bf(acc[mi][ni][r] + bv);
                }
            } else if (MODE == 1) {          // bf16 Vt (B,H,HD,S)
                short* ob = (short*)outp;
                const int h_ = n >> 6, d_ = n & 63;
                const int b_ = mb >> 11, s_ = mb & 2047;
                short4v pk;
#pragma unroll
                for (int r = 0; r < 4; r++) pk[r] = f2bf(acc[mi][ni][r] + bv);
                *(short4v*)(ob + ((size_t)((b_ * NHEADS + h_) * HD + d_)) * SEQ + s_) = pk;
            } else {                         // MODE 2: fp32 row-major
                float* of = (float*)outp;
#pragma unroll
                for (int r = 0; r < 4; r++)
                    of[(size_t)(mb + r) * 1024 + n] = acc[mi][ni][r] + bv;
            }
        }
    }
}

// ---------------- fused attention ----------------
// Q,K: bf16 head-major (B,H,S,HD).  Vt: bf16 (B,H,HD,S).
// attn_out: fp32 (B,H,S,S).  Xattn: bf16 (B,S,H*HD).
// Block = 256 thr = 4 waves; block handles (bh, 64 q rows); wave 16 q rows.
// sP is wave-private: no __syncthreads needed, only same-wave lgkmcnt ordering.
__global__ __launch_bounds__(256) void attn_kernel(const short* __restrict__ Q,
                                                   const short* __restrict__ K,
                                                   const short* __restrict__ Vt,
                                                   const int* __restrict__ mask,
                                                   float* __restrict__ attn_out,
                                                   short* __restrict__ Xattn) {
    __shared__ short sP[4][16][40];   // per-wave P tile, padded rows (80B)

    const int lane = threadIdx.x & 63;
    const int w    = threadIdx.x >> 6;
    const int l15  = lane & 15;
    const int quad = lane >> 4;
    const int qblk = blockIdx.x & 31;
    const int bh   = blockIdx.x >> 5;
    const int b    = bh >> 4;
    const int h    = bh & 15;
    const int q0   = qblk * 64 + w * 16;

    // Q fragments (head-major: row stride 64)
    const short* Qrow = Q + (size_t)(bh * SEQ + q0 + l15) * HD;
    const short8 aq0 = *(const short8*)(Qrow + quad * 8);
    const short8 aq1 = *(const short8*)(Qrow + 32 + quad * 8);

    const short* Kb   = K + (size_t)bh * SEQ * HD;   // + n*64 + d
    const int*   mrow = mask + b * SEQ;
    const float  scale = 0.125f;     // 1/sqrt(64)

    // ---- Pass A: exp row sums (energy bounded; no max subtraction) ----
    float rs[4] = {0.f, 0.f, 0.f, 0.f};
    {
        const short* kp = Kb + (size_t)l15 * HD;
        short8 nk0 = *(const short8*)(kp + quad * 8);
        short8 nk1 = *(const short8*)(kp + 32 + quad * 8);
        int nmv = mrow[l15];
        for (int n0 = 0; n0 < SEQ; n0 += 16) {
            const short8 ck0 = nk0, ck1 = nk1;
            const int cmv = nmv;
            if (n0 + 16 < SEQ) {                      // prefetch next K tile
                const short* kn = Kb + (size_t)(n0 + 16 + l15) * HD;
                nk0 = *(const short8*)(kn + quad * 8);
                nk1 = *(const short8*)(kn + 32 + quad * 8);
                nmv = mrow[n0 + 16 + l15];
            }
            float4v e = {0.f, 0.f, 0.f, 0.f};
            e = __builtin_amdgcn_mfma_f32_16x16x32_bf16(aq0, ck0, e, 0, 0, 0);
            e = __builtin_amdgcn_mfma_f32_16x16x32_bf16(aq1, ck1, e, 0, 0, 0);
#pragma unroll
            for (int r = 0; r < 4; r++) {
                float x = e[r] * scale;
                x = cmv ? x : -1e10f;
                rs[r] += __expf(x);
            }
        }
    }
#pragma unroll
    for (int r = 0; r < 4; r++) {
        float s = rs[r];
        s += __shfl_xor(s, 1, 64);
        s += __shfl_xor(s, 2, 64);
        s += __shfl_xor(s, 4, 64);
        s += __shfl_xor(s, 8, 64);
        rs[r] = 1.0f / s;            // 1/rowsum for row quad*4+r
    }

    // ---- Pass B: recompute scores, write probs, accumulate O = P*V ----
    float4v oacc[4];
#pragma unroll
    for (int i = 0; i < 4; i++)
#pragma unroll
        for (int j = 0; j < 4; j++) oacc[i][j] = 0.0f;

    float* pout = attn_out + (size_t)(bh * SEQ + q0) * SEQ;   // + m*SEQ + n
    const short* Vb = Vt + (size_t)bh * HD * SEQ;             // + d*SEQ + s

    short8 k00, k01, k10, k11;
    int mv0, mv1;
    {
        const short* k0p = Kb + (size_t)l15 * HD;
        const short* k1p = Kb + (size_t)(16 + l15) * HD;
        k00 = *(const short8*)(k0p + quad * 8);
        k01 = *(const short8*)(k0p + 32 + quad * 8);
        k10 = *(const short8*)(k1p + quad * 8);
        k11 = *(const short8*)(k1p + 32 + quad * 8);
        mv0 = mrow[l15];
        mv1 = mrow[16 + l15];
    }

    for (int n0 = 0; n0 < SEQ; n0 += 32) {
        const short8 c00 = k00, c01 = k01, c10 = k10, c11 = k11;
        const int cm0 = mv0, cm1 = mv1;

        // V tiles for this iteration: issued early, consumed after exp/stores
        short8 bv[4];
#pragma unroll
        for (int dn = 0; dn < 4; dn++)
            bv[dn] = *(const short8*)(Vb + (size_t)(dn * 16 + l15) * SEQ + n0 + quad * 8);

        if (n0 + 32 < SEQ) {                          // prefetch next K tiles
            const short* k0p = Kb + (size_t)(n0 + 32 + l15) * HD;
            const short* k1p = Kb + (size_t)(n0 + 48 + l15) * HD;
            k00 = *(const short8*)(k0p + quad * 8);
            k01 = *(const short8*)(k0p + 32 + quad * 8);
            k10 = *(const short8*)(k1p + quad * 8);
            k11 = *(const short8*)(k1p + 32 + quad * 8);
            mv0 = mrow[n0 + 32 + l15];
            mv1 = mrow[n0 + 48 + l15];
        }

        float4v e0 = {0.f, 0.f, 0.f, 0.f};
        float4v e1 = {0.f, 0.f, 0.f, 0.f};
        e0 = __builtin_amdgcn_mfma_f32_16x16x32_bf16(aq0, c00, e0, 0, 0, 0);
        e0 = __builtin_amdgcn_mfma_f32_16x16x32_bf16(aq1, c01, e0, 0, 0, 0);
        e1 = __builtin_amdgcn_mfma_f32_16x16x32_bf16(aq0, c10, e1, 0, 0, 0);
        e1 = __builtin_amdgcn_mfma_f32_16x16x32_bf16(aq1, c11, e1, 0, 0, 0);

#pragma unroll
        for (int r = 0; r < 4; r++) {
            const int m = quad * 4 + r;
            float x0 = e0[r] * scale;
            x0 = cm0 ? x0 : -1e10f;
            const float p0 = __expf(x0) * rs[r];
            pout[(size_t)m * SEQ + n0 + l15] = p0;
            sP[w][m][l15] = f2bf(p0);
            float x1 = e1[r] * scale;
            x1 = cm1 ? x1 : -1e10f;
            const float p1 = __expf(x1) * rs[r];
            pout[(size_t)m * SEQ + n0 + 16 + l15] = p1;
            sP[w][m][16 + l15] = f2bf(p1);
        }

        // same-wave ds_write -> ds_read ordering (no cross-wave sharing)
        asm volatile("s_waitcnt lgkmcnt(0)" ::: "memory");
        __builtin_amdgcn_sched_barrier(0);

        const short8 ap = *(const short8*)(&sP[w][l15][quad * 8]);
#pragma unroll
        for (int dn = 0; dn < 4; dn++)
            oacc[dn] = __builtin_amdgcn_mfma_f32_16x16x32_bf16(ap, bv[dn], oacc[dn], 0, 0, 0);
    }

    // write Xattn (bf16, concat-heads row-major)
#pragma unroll
    for (int dn = 0; dn < 4; dn++)
#pragma unroll
        for (int r = 0; r < 4; r++) {
            const int m = quad * 4 + r;
            Xattn[(size_t)(b * SEQ + q0 + m) * HID + h * HD + dn * 16 + l15] =
                f2bf(oacc[dn][r]);
        }
}

extern "C" void kernel_launch(void* const* d_in, const int* in_sizes, int n_in,
                              void* d_out, int out_size, void* d_ws, size_t ws_size,
                              hipStream_t stream) {
    const float* query  = (const float*)d_in[0];
    const float* key_in = (const float*)d_in[1];
    const float* value  = (const float*)d_in[2];
    const int*   mask   = (const int*)d_in[3];
    const float* Wq = (const float*)d_in[4];
    const float* bq = (const float*)d_in[5];
    const float* Wk = (const float*)d_in[6];
    const float* bk = (const float*)d_in[7];
    const float* Wv = (const float*)d_in[8];
    const float* bv = (const float*)d_in[9];
    const float* Wo = (const float*)d_in[10];
    const float* bo = (const float*)d_in[11];

    char* ws = (char*)d_ws;
    const size_t MiB = 1024 * 1024;
    short* Wq_b = (short*)(ws + 0 * MiB);
    short* Wk_b = (short*)(ws + 2 * MiB);
    short* Wv_b = (short*)(ws + 4 * MiB);
    short* Wo_b = (short*)(ws + 6 * MiB);
    short* Qw   = (short*)(ws + 8 * MiB);    // 16 MiB each
    short* Kw   = (short*)(ws + 24 * MiB);
    short* Vtw  = (short*)(ws + 40 * MiB);
    short* Xa   = (short*)(ws + 56 * MiB);   // end: 72 MiB
    short* T    = Xa;   // input-convert scratch; free until attn writes Xa

    const int wn4 = HID * HID / 4;           // weight convert (4 MiB fp32 each)
    cvt_f32_bf16<<<wn4 / 256, 256, 0, stream>>>(Wq, Wq_b, wn4);
    cvt_f32_bf16<<<wn4 / 256, 256, 0, stream>>>(Wk, Wk_b, wn4);
    cvt_f32_bf16<<<wn4 / 256, 256, 0, stream>>>(Wv, Wv_b, wn4);
    cvt_f32_bf16<<<wn4 / 256, 256, 0, stream>>>(Wo, Wo_b, wn4);

    const int an4 = BATCH * SEQ * HID / 4;   // activation convert (32 MiB fp32)
    const int GEMM_GRID = (BATCH * SEQ / 128) * (HID / 128);   // 512

    cvt_f32_bf16<<<an4 / 256, 256, 0, stream>>>(query, T, an4);
    gemm_bf16<3><<<GEMM_GRID, 256, 0, stream>>>(T, Wq_b, bq, Qw);
    cvt_f32_bf16<<<an4 / 256, 256, 0, stream>>>(key_in, T, an4);
    gemm_bf16<3><<<GEMM_GRID, 256, 0, stream>>>(T, Wk_b, bk, Kw);
    cvt_f32_bf16<<<an4 / 256, 256, 0, stream>>>(value, T, an4);
    gemm_bf16<1><<<GEMM_GRID, 256, 0, stream>>>(T, Wv_b, bv, Vtw);

    float* attn_out = (float*)d_out + (size_t)BATCH * SEQ * HID;
    attn_kernel<<<BATCH * NHEADS * (SEQ / 64), 256, 0, stream>>>(Qw, Kw, Vtw, mask,
                                                                 attn_out, Xa);

    gemm_bf16<2><<<GEMM_GRID, 256, 0, stream>>>(Xa, Wo_b, bo, d_out);
}